// Round 6
// baseline (743.514 us; speedup 1.0000x reference)
//
#include <hip/hip_runtime.h>
#include <math.h>
#include <float.h>
#include <limits.h>

#define N 8192
#define D 64
#define TOPK 32
#define TILE 128
#define CAP2 1024

typedef __attribute__((ext_vector_type(8))) short short8;
typedef __attribute__((ext_vector_type(4))) float float4v;

// orderable-uint encoding of float: a > b  <=>  ford(a) > ford(b)
__device__ __forceinline__ unsigned ford(float f) {
    unsigned u = __float_as_uint(f);
    return u ^ ((u & 0x80000000u) ? 0xFFFFFFFFu : 0x80000000u);
}
__device__ __forceinline__ float finv(unsigned u) {
    unsigned b = (u & 0x80000000u) ? (u ^ 0x80000000u) : ~u;
    return __uint_as_float(b);
}
// round-to-nearest-even fp32 -> bf16 bits
__device__ __forceinline__ unsigned short bf16rne(float f) {
    unsigned u = __float_as_uint(f);
    return (unsigned short)((u + 0x7FFFu + ((u >> 16) & 1u)) >> 16);
}
__device__ __forceinline__ float bf2f(unsigned short h) {
    return __uint_as_float((unsigned)h << 16);
}

// ---------------------------------------------------------------------------
// Kernel 0: zero the dense N*N section of d_out.
// ---------------------------------------------------------------------------
__global__ __launch_bounds__(256) void zero_kernel(float4* __restrict__ p)
{
    const int n4 = N * N / 4;
    const float4 zz = make_float4(0.f, 0.f, 0.f, 0.f);
    int stride = gridDim.x * 256;
    for (int i = blockIdx.x * 256 + threadIdx.x; i < n4; i += stride)
        p[i] = zz;
}

// ---------------------------------------------------------------------------
// Kernel 1: row norms -> nrm[0..2N); also zeros per-row candidate counters.
// ---------------------------------------------------------------------------
__global__ __launch_bounds__(256) void norms_kernel(
    const float* __restrict__ X1, const float* __restrict__ X2,
    float* __restrict__ nrm, int* __restrict__ gcnt)
{
    int id = blockIdx.x * blockDim.x + threadIdx.x;
    if (id >= 2 * N) return;
    if (id < N && gcnt) gcnt[id] = 0;
    const float* X = (id < N) ? X1 : X2;
    int r = (id < N) ? id : id - N;
    const float4* p = (const float4*)(X + (size_t)r * D);
    float s = 0.f;
#pragma unroll
    for (int q = 0; q < D / 4; ++q) {
        float4 v = p[q];
        s += v.x * v.x + v.y * v.y + v.z * v.z + v.w * v.w;
    }
    nrm[id] = s;
}

// ---------------------------------------------------------------------------
// Kernel 2 (MFMA): 3-way bf16 split GEMM (deterministic: pass1 and pass2
// produce bit-identical values). mode 0: emit tmax only (no matrix store).
// mode 1: push survivors >= thr[row] to global per-row candidate buffers.
// mode 2 (legacy small-ws): store matrix to dst + tmax.
// ---------------------------------------------------------------------------
__global__ __launch_bounds__(256, 1) void dist_kernel(
    const float* __restrict__ X1, const float* __restrict__ X2,
    const float* __restrict__ nrm, float* __restrict__ dst,
    float* __restrict__ tmax, const float* __restrict__ thr,
    int* __restrict__ gcnt, unsigned long long* __restrict__ gcand,
    int mode)
{
    __shared__ __align__(16) short Ah[128 * 64], Am[128 * 64], Al[128 * 64];
    __shared__ __align__(16) short Bh[128 * 64], Bm[128 * 64], Bl[128 * 64];
    __shared__ float tpart[128][2];
    __shared__ float sthr[128];

    const int t = threadIdx.x;
    const int row0 = blockIdx.y * TILE;
    const int col0 = blockIdx.x * TILE;

    if (mode == 1 && t < 128) sthr[t] = thr[row0 + t];

    // ---- stage: fp32 -> (hi,mid,lo) bf16 splits in LDS ----
#pragma unroll
    for (int q = 0; q < 8; ++q) {
        int g  = q * 256 + t;
        int mtx = g >> 10;
        int gg = g & 1023;
        int rr = gg >> 3;
        int cc = gg & 7;
        const float* src = (mtx ? X2 : X1) +
                           (size_t)((mtx ? col0 : row0) + rr) * D + 8 * cc;
        float4 xa = *(const float4*)src;
        float4 xb = *(const float4*)(src + 4);
        float xs[8] = {xa.x, xa.y, xa.z, xa.w, xb.x, xb.y, xb.z, xb.w};
        short8 hv, mv, lv;
#pragma unroll
        for (int j = 0; j < 8; ++j) {
            float f = xs[j];
            unsigned short h = bf16rne(f);
            float rm = f - bf2f(h);
            unsigned short m = bf16rne(rm);
            float rl = rm - bf2f(m);
            unsigned short l = bf16rne(rl);
            hv[j] = (short)h; mv[j] = (short)m; lv[j] = (short)l;
        }
        int off = rr * 8 + (cc ^ (rr & 7));
        if (mtx == 0) {
            ((short8*)Ah)[off] = hv; ((short8*)Am)[off] = mv; ((short8*)Al)[off] = lv;
        } else {
            ((short8*)Bh)[off] = hv; ((short8*)Bm)[off] = mv; ((short8*)Bl)[off] = lv;
        }
    }
    __syncthreads();

    const int w     = t >> 6;
    const int lane  = t & 63;
    const int RW    = (w >> 1) * 64;
    const int CW    = (w & 1) * 64;
    const int rq    = lane >> 4;
    const int rlow  = lane & 15;

    float4v acc[4][4];
#pragma unroll
    for (int i = 0; i < 4; ++i)
#pragma unroll
        for (int j = 0; j < 4; ++j)
            acc[i][j] = (float4v){0.f, 0.f, 0.f, 0.f};

#pragma unroll
    for (int ks = 0; ks < 2; ++ks) {
        const int cidx = 4 * ks + rq;
        short8 bh[4], bm[4], bl[4];
#pragma unroll
        for (int tn = 0; tn < 4; ++tn) {
            int rr = CW + 16 * tn + rlow;
            int off = rr * 8 + (cidx ^ (rr & 7));
            bh[tn] = ((const short8*)Bh)[off];
            bm[tn] = ((const short8*)Bm)[off];
            bl[tn] = ((const short8*)Bl)[off];
        }
#pragma unroll
        for (int tm = 0; tm < 4; ++tm) {
            int rr = RW + 16 * tm + rlow;
            int off = rr * 8 + (cidx ^ (rr & 7));
            short8 ah = ((const short8*)Ah)[off];
            short8 am = ((const short8*)Am)[off];
            short8 al = ((const short8*)Al)[off];
#pragma unroll
            for (int tn = 0; tn < 4; ++tn) {
                float4v c = acc[tm][tn];
                c = __builtin_amdgcn_mfma_f32_16x16x32_bf16(ah, bh[tn], c, 0, 0, 0);
                c = __builtin_amdgcn_mfma_f32_16x16x32_bf16(ah, bm[tn], c, 0, 0, 0);
                c = __builtin_amdgcn_mfma_f32_16x16x32_bf16(am, bh[tn], c, 0, 0, 0);
                c = __builtin_amdgcn_mfma_f32_16x16x32_bf16(ah, bl[tn], c, 0, 0, 0);
                c = __builtin_amdgcn_mfma_f32_16x16x32_bf16(al, bh[tn], c, 0, 0, 0);
                c = __builtin_amdgcn_mfma_f32_16x16x32_bf16(am, bm[tn], c, 0, 0, 0);
                acc[tm][tn] = c;
            }
        }
    }

    // ---- epilogue ----
    float na[4][4], nb[4];
#pragma unroll
    for (int tm = 0; tm < 4; ++tm)
#pragma unroll
        for (int reg = 0; reg < 4; ++reg)
            na[tm][reg] = nrm[row0 + RW + 16 * tm + 4 * rq + reg];
#pragma unroll
    for (int tn = 0; tn < 4; ++tn)
        nb[tn] = nrm[N + col0 + CW + 16 * tn + rlow];

    if (mode == 1) {
        // push survivors >= thr[row] into global per-row candidate lists
#pragma unroll
        for (int tm = 0; tm < 4; ++tm) {
#pragma unroll
            for (int tn = 0; tn < 4; ++tn) {
#pragma unroll
                for (int reg = 0; reg < 4; ++reg) {
                    int row_local = RW + 16 * tm + 4 * rq + reg;
                    int col_local = CW + 16 * tn + rlow;
                    float sq = na[tm][reg] + nb[tn] - 2.0f * acc[tm][tn][reg];
                    float v = -fmaxf(sq, 0.0f);
                    if (v >= sthr[row_local]) {
                        int rrow = row0 + row_local;
                        int p = atomicAdd(&gcnt[rrow], 1);
                        if (p < CAP2) {
                            int j = col0 + col_local;
                            gcand[(size_t)rrow * CAP2 + p] =
                                ((unsigned long long)ford(v) << 32) |
                                (unsigned)(8191 - j);
                        }
                    }
                }
            }
        }
    } else {
        float rmx[4][4];
#pragma unroll
        for (int tm = 0; tm < 4; ++tm)
#pragma unroll
            for (int reg = 0; reg < 4; ++reg)
                rmx[tm][reg] = -FLT_MAX;
#pragma unroll
        for (int tm = 0; tm < 4; ++tm) {
#pragma unroll
            for (int tn = 0; tn < 4; ++tn) {
#pragma unroll
                for (int reg = 0; reg < 4; ++reg) {
                    int row_local = RW + 16 * tm + 4 * rq + reg;
                    int col_local = CW + 16 * tn + rlow;
                    float sq = na[tm][reg] + nb[tn] - 2.0f * acc[tm][tn][reg];
                    float v = -fmaxf(sq, 0.0f);
                    if (mode == 2)
                        dst[(size_t)(row0 + row_local) * N + col0 + col_local] = v;
                    rmx[tm][reg] = fmaxf(rmx[tm][reg], v);
                }
            }
        }
#pragma unroll
        for (int tm = 0; tm < 4; ++tm) {
#pragma unroll
            for (int reg = 0; reg < 4; ++reg) {
                float mv = rmx[tm][reg];
                mv = fmaxf(mv, __shfl_xor(mv, 1));
                mv = fmaxf(mv, __shfl_xor(mv, 2));
                mv = fmaxf(mv, __shfl_xor(mv, 4));
                mv = fmaxf(mv, __shfl_xor(mv, 8));
                if (rlow == 0)
                    tpart[RW + 16 * tm + 4 * rq + reg][w & 1] = mv;
            }
        }
        __syncthreads();
        if ((w & 1) == 0) {
            int row_abs = RW + lane;
            float tv = fmaxf(tpart[row_abs][0], tpart[row_abs][1]);
            tmax[(size_t)(row0 + row_abs) * 64 + blockIdx.x] = tv;
        }
    }
}

// ---------------------------------------------------------------------------
// Kernel T: thr[r] = 32nd-largest of the row's 64 tile-maxes (wave per row).
// ---------------------------------------------------------------------------
__global__ __launch_bounds__(256) void thr_kernel(
    const float* __restrict__ tmax, float* __restrict__ thr)
{
    const int t = threadIdx.x;
    const int w = t >> 6;
    const int lane = t & 63;
    const int r = blockIdx.x * 4 + w;
    float tm = tmax[(size_t)r * 64 + lane];
    unsigned km = ford(tm);
    int rk = 0;
#pragma unroll
    for (int l = 0; l < 64; ++l) {
        unsigned o = __shfl(km, l);
        rk += (o > km || (o == km && l < lane)) ? 1 : 0;
    }
    unsigned long long bm = __ballot(rk == 31);
    float tv = __shfl(tm, __ffsll((long long)bm) - 1);
    if (lane == 0) thr[r] = tv;
}

// ---------------------------------------------------------------------------
// Kernel S: wave per row. Read its candidate list (avg ~44, cap 1024),
// exact top-32 via u64-key argmax, sqrt+softmax, scatter into pre-zeroed out.
// Overflow fallback (never on this data): iterative key-descent recompute.
// ---------------------------------------------------------------------------
__global__ __launch_bounds__(256) void select_kernel(
    const int* __restrict__ gcnt, const unsigned long long* __restrict__ gcand,
    const float* __restrict__ X1, const float* __restrict__ X2,
    const float* __restrict__ nrm,
    float* __restrict__ out, float* __restrict__ score_out)
{
    __shared__ unsigned long long cand[4][CAP2];   // 32 KB
    __shared__ float rowA[4][64];

    const int t    = threadIdx.x;
    const int w    = t >> 6;
    const int lane = t & 63;
    const int r    = blockIdx.x * 4 + w;

    const int ntot = gcnt[r];
    unsigned long long mykey = 0ull;

    if (ntot <= CAP2) {
        for (int q = lane; q < ntot; q += 64)
            cand[w][q] = gcand[(size_t)r * CAP2 + q];
        __builtin_amdgcn_s_waitcnt(0);   // global loads + LDS writes done
        const int n = ntot;
        for (int it = 0; it < TOPK; ++it) {
            unsigned long long b = 0ull; int bp = 0;
            for (int q = lane; q < n; q += 64) {
                unsigned long long kk = cand[w][q];
                if (kk > b) { b = kk; bp = q; }
            }
            for (int off = 32; off > 0; off >>= 1) {
                unsigned long long ob = __shfl_down(b, off);
                int op = __shfl_down(bp, off);
                if (ob > b) { b = ob; bp = op; }
            }
            unsigned long long b0 = __shfl(b, 0);
            int bp0 = __shfl(bp, 0);
            if (lane == it) { mykey = b0; cand[w][bp0] = 0ull; }
        }
    } else {
        // safety net: exact selection by strict key-descent, recomputing row
        if (lane < 64) rowA[w][lane] = X1[(size_t)r * D + lane];
        __builtin_amdgcn_s_waitcnt(0);
        const float na_ = nrm[r];
        unsigned long long kprev = ~0ull;
        for (int it = 0; it < TOPK; ++it) {
            unsigned long long best = 0ull;
            for (int c = 0; c < 128; ++c) {
                int col = c * 64 + lane;
                const float4* x2p = (const float4*)(X2 + (size_t)col * D);
                float dot = 0.f;
#pragma unroll
                for (int k = 0; k < 16; ++k) {
                    float4 b4 = x2p[k];
                    dot += rowA[w][4 * k + 0] * b4.x + rowA[w][4 * k + 1] * b4.y +
                           rowA[w][4 * k + 2] * b4.z + rowA[w][4 * k + 3] * b4.w;
                }
                float sq = na_ + nrm[N + col] - 2.0f * dot;
                float v = -fmaxf(sq, 0.0f);
                unsigned long long key =
                    ((unsigned long long)ford(v) << 32) | (unsigned)(8191 - col);
                if (key < kprev && key > best) best = key;
            }
            for (int off = 32; off > 0; off >>= 1) {
                unsigned long long ob = __shfl_down(best, off);
                if (ob > best) best = ob;
            }
            unsigned long long b0 = __shfl(best, 0);
            kprev = b0;
            if (lane == it) mykey = b0;
        }
    }

    // ---- sqrt + softmax on the 32 winners (rank == lane) ----
    float myv = 0.f; int myj = 0;
    if (lane < TOPK) {
        float sv = finv((unsigned)(mykey >> 32));   // stored -max(sq,0)
        myv = -sqrtf(-sv);
        myj = 8191 - (int)(mykey & 0xFFFFFFFFu);
    }
    float Mx = __shfl(myv, 0);
    float e = (lane < TOPK) ? expf(myv - Mx) : 0.f;
    float Z = e;
    for (int off = 32; off > 0; off >>= 1) Z += __shfl_xor(Z, off);
    float s = e / Z;
    if (lane < TOPK) {
        score_out[(size_t)r * TOPK + lane] = s;
        out[(size_t)r * N + myj] = s;      // out pre-zeroed by zero_kernel
    }
}

// ---------------------------------------------------------------------------
// Legacy small-ws fallback: stream matrix (in out), self-zero, scatter.
// ---------------------------------------------------------------------------
__global__ __launch_bounds__(256) void topk_legacy_kernel(
    float* __restrict__ out, float* __restrict__ score_out,
    const float* __restrict__ tmax, int have_tmax)
{
    __shared__ unsigned long long cand[4][CAP2];
    __shared__ int scnt[4];

    const int t    = threadIdx.x;
    const int w    = t >> 6;
    const int lane = t & 63;
    const int r    = blockIdx.x * 4 + w;
    float* rowout = out + (size_t)r * N;
    const float4* row4 = (const float4*)rowout;

    float thr;
    if (have_tmax) {
        float tm = tmax[(size_t)r * 64 + lane];
        unsigned km = ford(tm);
        int rk = 0;
#pragma unroll
        for (int l = 0; l < 64; ++l) {
            unsigned o = __shfl(km, l);
            rk += (o > km || (o == km && l < lane)) ? 1 : 0;
        }
        unsigned long long bm = __ballot(rk == 31);
        thr = __shfl(tm, __ffsll((long long)bm) - 1);
    } else {
        float lm = -FLT_MAX;
#pragma unroll 8
        for (int c = 0; c < 32; ++c) {
            float4 x = row4[c * 64 + lane];
            lm = fmaxf(lm, fmaxf(fmaxf(x.x, x.y), fmaxf(x.z, x.w)));
        }
        thr = lm;
        for (int off = 32; off > 0; off >>= 1)
            thr = fminf(thr, __shfl_xor(thr, off));
    }

    if (lane == 0) scnt[w] = 0;
    __builtin_amdgcn_s_waitcnt(0xC07F);
    for (int c = 0; c < 32; ++c) {
        float4 x = row4[c * 64 + lane];
        float vs[4] = {x.x, x.y, x.z, x.w};
#pragma unroll
        for (int q = 0; q < 4; ++q) {
            float v = vs[q];
            if (v >= thr) {
                int p = atomicAdd(&scnt[w], 1);
                if (p < CAP2) {
                    int j = 4 * (c * 64 + lane) + q;
                    cand[w][p] = ((unsigned long long)ford(v) << 32) |
                                 (unsigned)(8191 - j);
                }
            }
        }
    }
    __builtin_amdgcn_s_waitcnt(0xC07F);
    const int n = min(scnt[w], CAP2);

    unsigned long long mykey = 0ull;
    for (int it = 0; it < TOPK; ++it) {
        unsigned long long b = 0ull; int bp = 0;
        for (int q = lane; q < n; q += 64) {
            unsigned long long kk = cand[w][q];
            if (kk > b) { b = kk; bp = q; }
        }
        for (int off = 32; off > 0; off >>= 1) {
            unsigned long long ob = __shfl_down(b, off);
            int op = __shfl_down(bp, off);
            if (ob > b) { b = ob; bp = op; }
        }
        unsigned long long b0 = __shfl(b, 0);
        int bp0 = __shfl(bp, 0);
        if (lane == it) { mykey = b0; cand[w][bp0] = 0ull; }
    }

    float myv = 0.f; int myj = 0;
    if (lane < TOPK) {
        float sv = finv((unsigned)(mykey >> 32));
        myv = -sqrtf(-sv);
        myj = 8191 - (int)(mykey & 0xFFFFFFFFu);
    }
    float Mx = __shfl(myv, 0);
    float e = (lane < TOPK) ? expf(myv - Mx) : 0.f;
    float Z = e;
    for (int off = 32; off > 0; off >>= 1) Z += __shfl_xor(Z, off);
    float s = e / Z;
    if (lane < TOPK) score_out[(size_t)r * TOPK + lane] = s;

    const float4 zz = make_float4(0.f, 0.f, 0.f, 0.f);
#pragma unroll 8
    for (int c = 0; c < 32; ++c) ((float4*)rowout)[c * 64 + lane] = zz;
    __builtin_amdgcn_s_waitcnt(0x0F70);   // vmcnt(0)
    if (lane < TOPK) rowout[myj] = s;
}

// ---------------------------------------------------------------------------
extern "C" void kernel_launch(void* const* d_in, const int* in_sizes, int n_in,
                              void* d_out, int out_size, void* d_ws, size_t ws_size,
                              hipStream_t stream)
{
    const float* X1 = (const float*)d_in[0];
    const float* X2 = (const float*)d_in[1];
    float* out  = (float*)d_out;

    // ws layout
    float* nrm  = (float*)d_ws;                       // 2N floats
    float* tmax = nrm + 2 * N;                        // N*64 floats (2 MB)
    float* thr  = tmax + (size_t)N * 64;              // N floats
    int*   gcnt = (int*)(thr + N);                    // N ints
    unsigned long long* gcand =
        (unsigned long long*)(gcnt + N);              // N*CAP2 u64 (64 MB)

    size_t need_fast = (size_t)((char*)(gcand + (size_t)N * CAP2) - (char*)d_ws);
    size_t need_tmax = (size_t)((char*)gcnt - (char*)d_ws);
    dim3 grid(N / TILE, N / TILE);

    if (ws_size >= need_fast) {
        norms_kernel<<<(2 * N + 255) / 256, 256, 0, stream>>>(X1, X2, nrm, gcnt);
        dist_kernel<<<grid, 256, 0, stream>>>(X1, X2, nrm, nullptr, tmax,
                                              nullptr, nullptr, nullptr, 0);
        thr_kernel<<<N / 4, 256, 0, stream>>>(tmax, thr);
        zero_kernel<<<4096, 256, 0, stream>>>((float4*)out);
        dist_kernel<<<grid, 256, 0, stream>>>(X1, X2, nrm, nullptr, nullptr,
                                              thr, gcnt, gcand, 1);
        select_kernel<<<N / 4, 256, 0, stream>>>(gcnt, gcand, X1, X2, nrm,
                                                 out, out + (size_t)N * N);
    } else {
        int have_tmax = (ws_size >= need_tmax) ? 1 : 0;
        norms_kernel<<<(2 * N + 255) / 256, 256, 0, stream>>>(X1, X2, nrm, nullptr);
        dist_kernel<<<grid, 256, 0, stream>>>(X1, X2, nrm, out, tmax,
                                              nullptr, nullptr, nullptr, 2);
        topk_legacy_kernel<<<N / 4, 256, 0, stream>>>(out, out + (size_t)N * N,
                                                      tmax, have_tmax);
    }
}

// Round 7
// 482.846 us; speedup vs baseline: 1.5399x; 1.5399x over previous
//
#include <hip/hip_runtime.h>
#include <math.h>
#include <float.h>
#include <limits.h>

#define N 8192
#define D 64
#define TOPK 32
#define TILE 128
#define CAP 1024

typedef __attribute__((ext_vector_type(4))) float float4v;

// orderable-uint encoding of float: a > b  <=>  ford(a) > ford(b)
__device__ __forceinline__ unsigned ford(float f) {
    unsigned u = __float_as_uint(f);
    return u ^ ((u & 0x80000000u) ? 0xFFFFFFFFu : 0x80000000u);
}
__device__ __forceinline__ float finv(unsigned u) {
    unsigned b = (u & 0x80000000u) ? (u ^ 0x80000000u) : ~u;
    return __uint_as_float(b);
}

// ---------------------------------------------------------------------------
// Kernel 1: row norms of X1 and X2 -> nrm[0..2N)
// ---------------------------------------------------------------------------
__global__ __launch_bounds__(256) void norms_kernel(
    const float* __restrict__ X1, const float* __restrict__ X2,
    float* __restrict__ nrm)
{
    int id = blockIdx.x * blockDim.x + threadIdx.x;
    if (id >= 2 * N) return;
    const float* X = (id < N) ? X1 : X2;
    int r = (id < N) ? id : id - N;
    const float4* p = (const float4*)(X + (size_t)r * D);
    float s = 0.f;
#pragma unroll
    for (int q = 0; q < D / 4; ++q) {
        float4 v = p[q];
        s += v.x * v.x + v.y * v.y + v.z * v.z + v.w * v.w;
    }
    nrm[id] = s;
}

// ---------------------------------------------------------------------------
// Kernel 2 (fp32, PROVEN ~113-157us): stores -max(sq,0) (monotone proxy for
// -sqrt; sqrt applied to the 32 winners in topk -> identical final values).
// Emits per-row 128-col tile maxes. 128x128 tile, 8x8/thread, XOR-swizzled
// LDS (conflict-free b128), 64 KB LDS -> 2 blocks/CU.
// ---------------------------------------------------------------------------
__global__ __launch_bounds__(256, 2) void dist_kernel(
    const float* __restrict__ X1, const float* __restrict__ X2,
    const float* __restrict__ nrm, float* __restrict__ dst,
    float* __restrict__ tmax, int have_tmax)
{
    __shared__ float As[D * TILE];
    __shared__ float Bs[D * TILE];

    const int t = threadIdx.x;
    const int row0 = blockIdx.y * TILE;
    const int col0 = blockIdx.x * TILE;

#pragma unroll
    for (int p = 0; p < 8; ++p) {
        int lin = p * 256 + t;
        int r   = lin >> 4;
        int d4  = (lin & 15) << 2;
        int g   = (d4 >> 2) & 7;
        int cb  = r ^ (g << 3);
        float4 a = *(const float4*)(X1 + (size_t)(row0 + r) * D + d4);
        As[(d4 + 0) * TILE + cb] = a.x;
        As[(d4 + 1) * TILE + cb] = a.y;
        As[(d4 + 2) * TILE + cb] = a.z;
        As[(d4 + 3) * TILE + cb] = a.w;
        float4 b = *(const float4*)(X2 + (size_t)(col0 + r) * D + d4);
        Bs[(d4 + 0) * TILE + cb] = b.x;
        Bs[(d4 + 1) * TILE + cb] = b.y;
        Bs[(d4 + 2) * TILE + cb] = b.z;
        Bs[(d4 + 3) * TILE + cb] = b.w;
    }
    __syncthreads();

    const int tx = t & 15;
    const int ty = t >> 4;
    float acc[8][8] = {};

#pragma unroll 8
    for (int k = 0; k < D; ++k) {
        int gk  = (k >> 2) & 7;
        int ab  = k * TILE + ((ty ^ gk) << 3);
        int bb0 = k * TILE + ((4 * tx) ^ (gk << 3));
        float4 a0 = *(const float4*)&As[ab];
        float4 a1 = *(const float4*)&As[ab + 4];
        float4 b0 = *(const float4*)&Bs[bb0];
        float4 b1 = *(const float4*)&Bs[bb0 + 64];
        float av[8] = {a0.x, a0.y, a0.z, a0.w, a1.x, a1.y, a1.z, a1.w};
        float bv[8] = {b0.x, b0.y, b0.z, b0.w, b1.x, b1.y, b1.z, b1.w};
#pragma unroll
        for (int i = 0; i < 8; ++i)
#pragma unroll
            for (int j = 0; j < 8; ++j)
                acc[i][j] += av[i] * bv[j];
    }

    float na[8], nb[8];
#pragma unroll
    for (int i = 0; i < 8; ++i) na[i] = nrm[row0 + 8 * ty + i];
#pragma unroll
    for (int q = 0; q < 4; ++q) {
        nb[q]     = nrm[N + col0 + 4 * tx + q];
        nb[4 + q] = nrm[N + col0 + 64 + 4 * tx + q];
    }

    float rmax[8];
#pragma unroll
    for (int i = 0; i < 8; ++i) rmax[i] = -FLT_MAX;

#pragma unroll
    for (int i = 0; i < 8; ++i) {
        float* po = dst + (size_t)(row0 + 8 * ty + i) * N + col0 + 4 * tx;
        float4 o0, o1;
        float* f0 = (float*)&o0;
        float* f1 = (float*)&o1;
#pragma unroll
        for (int q = 0; q < 4; ++q) {
            float s0 = na[i] + nb[q] - 2.0f * acc[i][q];
            f0[q] = -fmaxf(s0, 0.0f);
            float s1 = na[i] + nb[4 + q] - 2.0f * acc[i][4 + q];
            f1[q] = -fmaxf(s1, 0.0f);
            rmax[i] = fmaxf(rmax[i], fmaxf(f0[q], f1[q]));
        }
        *(float4*)po        = o0;
        *(float4*)(po + 64) = o1;
    }

    if (have_tmax) {
#pragma unroll
        for (int i = 0; i < 8; ++i) {
            float mv = rmax[i];
            mv = fmaxf(mv, __shfl_down(mv, 8, 16));
            mv = fmaxf(mv, __shfl_down(mv, 4, 16));
            mv = fmaxf(mv, __shfl_down(mv, 2, 16));
            mv = fmaxf(mv, __shfl_down(mv, 1, 16));
            if (tx == 0)
                tmax[(size_t)(row0 + 8 * ty + i) * 64 + blockIdx.x] = mv;
        }
    }
}

// ---------------------------------------------------------------------------
// Kernel 3 (PROVEN): one wave per row. thr = 32nd-largest tile-max (sound).
// Stream all 64 tiles of src coalesced, push survivors >= thr into per-wave
// LDS u64 keys, write zeros to out inline (NONTEMPORAL: don't evict the ws
// matrix from L3 under our own reads), 32x shfl argmax, sqrt+softmax, scatter.
// ---------------------------------------------------------------------------
__global__ __launch_bounds__(256) void topk_kernel(
    const float* __restrict__ src, float* __restrict__ out,
    float* __restrict__ score_out, const float* __restrict__ tmax,
    int have_tmax)
{
    __shared__ unsigned long long cand[4][CAP];   // 32 KB
    __shared__ int scnt[4];

    const int t    = threadIdx.x;
    const int w    = t >> 6;
    const int lane = t & 63;
    const int r    = blockIdx.x * 4 + w;
    const float4* row4 = (const float4*)(src + (size_t)r * N);
    float4v* rowz = (float4v*)(out + (size_t)r * N);
    float* rowout = out + (size_t)r * N;

    // ---- threshold ----
    float thr;
    if (have_tmax) {
        float tm = tmax[(size_t)r * 64 + lane];
        unsigned km = ford(tm);
        int rk = 0;
#pragma unroll
        for (int l = 0; l < 64; ++l) {
            unsigned o = __shfl(km, l);
            rk += (o > km || (o == km && l < lane)) ? 1 : 0;
        }
        unsigned long long bm = __ballot(rk == 31);
        thr = __shfl(tm, __ffsll((long long)bm) - 1);
    } else {
        float lm = -FLT_MAX;
#pragma unroll 8
        for (int c = 0; c < 32; ++c) {
            float4 x = row4[c * 64 + lane];
            lm = fmaxf(lm, fmaxf(fmaxf(x.x, x.y), fmaxf(x.z, x.w)));
        }
        thr = lm;   // min of per-lane maxes: sound (>=64 survivors)
        for (int off = 32; off > 0; off >>= 1)
            thr = fminf(thr, __shfl_xor(thr, off));
    }

    if (lane == 0) scnt[w] = 0;
    __builtin_amdgcn_s_waitcnt(0xC07F);   // lgkmcnt(0)

    // ---- stream + compact + nontemporal zero-fill of out ----
    const float4v zz = (float4v){0.f, 0.f, 0.f, 0.f};
    for (int c0 = 0; c0 < 32; c0 += 4) {
        float4 xs[4];
#pragma unroll
        for (int u = 0; u < 4; ++u) xs[u] = row4[(c0 + u) * 64 + lane];
#pragma unroll
        for (int u = 0; u < 4; ++u)
            __builtin_nontemporal_store(zz, &rowz[(c0 + u) * 64 + lane]);
#pragma unroll
        for (int u = 0; u < 4; ++u) {
            float vs[4] = {xs[u].x, xs[u].y, xs[u].z, xs[u].w};
#pragma unroll
            for (int q = 0; q < 4; ++q) {
                float v = vs[q];
                if (v >= thr) {
                    int p = atomicAdd(&scnt[w], 1);
                    if (p < CAP) {   // expected survivors ~44 << CAP
                        int j = 4 * ((c0 + u) * 64 + lane) + q;
                        cand[w][p] = ((unsigned long long)ford(v) << 32) |
                                     (unsigned)(8191 - j);
                    }
                }
            }
        }
    }
    __builtin_amdgcn_s_waitcnt(0xC07F);   // lgkmcnt(0): pushes visible
    const int n = min(scnt[w], CAP);

    // ---- 32 x wave argmax over packed keys (value desc, index asc) ----
    unsigned long long mykey = 0ull;
    for (int it = 0; it < TOPK; ++it) {
        unsigned long long b = 0ull; int bp = 0;
        for (int q = lane; q < n; q += 64) {
            unsigned long long kk = cand[w][q];
            if (kk > b) { b = kk; bp = q; }
        }
        for (int off = 32; off > 0; off >>= 1) {
            unsigned long long ob = __shfl_down(b, off);
            int op = __shfl_down(bp, off);
            if (ob > b) { b = ob; bp = op; }
        }
        unsigned long long b0 = __shfl(b, 0);
        int bp0 = __shfl(bp, 0);
        if (lane == it) { mykey = b0; cand[w][bp0] = 0ull; }
    }

    // ---- sqrt + softmax on the 32 winners (rank == lane) ----
    float myv = 0.f; int myj = 0;
    if (lane < TOPK) {
        float sv = finv((unsigned)(mykey >> 32));   // stored -max(sq,0)
        myv = -sqrtf(-sv);
        myj = 8191 - (int)(mykey & 0xFFFFFFFFu);
    }
    float Mx = __shfl(myv, 0);
    float e = (lane < TOPK) ? expf(myv - Mx) : 0.f;
    float Z = e;
    for (int off = 32; off > 0; off >>= 1) Z += __shfl_xor(Z, off);
    float s = e / Z;
    if (lane < TOPK) score_out[(size_t)r * TOPK + lane] = s;

    __builtin_amdgcn_s_waitcnt(0x0F70);   // vmcnt(0): zeros drained
    if (lane < TOPK) rowout[myj] = s;
}

// ---------------------------------------------------------------------------
extern "C" void kernel_launch(void* const* d_in, const int* in_sizes, int n_in,
                              void* d_out, int out_size, void* d_ws, size_t ws_size,
                              hipStream_t stream)
{
    const float* X1 = (const float*)d_in[0];
    const float* X2 = (const float*)d_in[1];
    float* out  = (float*)d_out;

    float* nrm  = (float*)d_ws;                 // 2N floats
    float* tmax = nrm + 2 * N;                  // N*64 floats (2 MB)
    float* dmat = tmax + (size_t)N * 64;        // N*N floats (256 MB)

    size_t need_tmax = (size_t)(2 * N + (size_t)N * 64) * sizeof(float);
    size_t need_full = need_tmax + (size_t)N * N * sizeof(float);
    int have_tmax = (ws_size >= need_tmax) ? 1 : 0;
    int fastmode  = (ws_size >= need_full) ? 1 : 0;

    float* dst = fastmode ? dmat : out;   // fallback: matrix in out, topk self-zeroes

    norms_kernel<<<(2 * N + 255) / 256, 256, 0, stream>>>(X1, X2, nrm);

    dim3 grid(N / TILE, N / TILE);
    dist_kernel<<<grid, 256, 0, stream>>>(X1, X2, nrm, dst, tmax, have_tmax);

    topk_kernel<<<N / 4, 256, 0, stream>>>(dst, out, out + (size_t)N * N,
                                           tmax, have_tmax);
}

// Round 8
// 482.660 us; speedup vs baseline: 1.5405x; 1.0004x over previous
//
#include <hip/hip_runtime.h>
#include <math.h>
#include <float.h>
#include <limits.h>

#define N 8192
#define D 64
#define TOPK 32
#define TILE 128
#define CAP 1024

typedef __attribute__((ext_vector_type(8))) short short8;
typedef __attribute__((ext_vector_type(4))) float float4v;

// orderable-uint encoding of float: a > b  <=>  ford(a) > ford(b)
__device__ __forceinline__ unsigned ford(float f) {
    unsigned u = __float_as_uint(f);
    return u ^ ((u & 0x80000000u) ? 0xFFFFFFFFu : 0x80000000u);
}
__device__ __forceinline__ float finv(unsigned u) {
    unsigned b = (u & 0x80000000u) ? (u ^ 0x80000000u) : ~u;
    return __uint_as_float(b);
}
__device__ __forceinline__ unsigned short bf16rne(float f) {
    unsigned u = __float_as_uint(f);
    return (unsigned short)((u + 0x7FFFu + ((u >> 16) & 1u)) >> 16);
}
__device__ __forceinline__ float bf2f(unsigned short h) {
    return __uint_as_float((unsigned)h << 16);
}

// ---------------------------------------------------------------------------
// Kernel P: pre-split X1,X2 -> bf16 hi/mid/lo arrays [row][k] row-major (6 MB,
// L2-resident). One 8-elem chunk per thread. Residual <= 2^-27|x|.
// ---------------------------------------------------------------------------
__global__ __launch_bounds__(256) void presplit_kernel(
    const float* __restrict__ X1, const float* __restrict__ X2,
    short* __restrict__ X1h, short* __restrict__ X1m, short* __restrict__ X1l,
    short* __restrict__ X2h, short* __restrict__ X2m, short* __restrict__ X2l)
{
    int id = blockIdx.x * 256 + threadIdx.x;      // 0 .. 2*N*8-1
    if (id >= 2 * N * 8) return;
    int mtx = (id >= N * 8);
    int g   = id & (N * 8 - 1);
    const float* src = (mtx ? X2 : X1) + (size_t)g * 8;
    short* dh = mtx ? X2h : X1h;
    short* dm = mtx ? X2m : X1m;
    short* dl = mtx ? X2l : X1l;
    float4 a = *(const float4*)src;
    float4 b = *(const float4*)(src + 4);
    float xs[8] = {a.x, a.y, a.z, a.w, b.x, b.y, b.z, b.w};
    short8 hv, mv, lv;
#pragma unroll
    for (int j = 0; j < 8; ++j) {
        float f = xs[j];
        unsigned short h = bf16rne(f);
        float rm = f - bf2f(h);
        unsigned short m = bf16rne(rm);
        float rl = rm - bf2f(m);
        hv[j] = (short)h; mv[j] = (short)m; lv[j] = (short)bf16rne(rl);
    }
    ((short8*)dh)[g] = hv;
    ((short8*)dm)[g] = mv;
    ((short8*)dl)[g] = lv;
}

// ---------------------------------------------------------------------------
// Kernel 1: row norms of X1 and X2 -> nrm[0..2N)
// ---------------------------------------------------------------------------
__global__ __launch_bounds__(256) void norms_kernel(
    const float* __restrict__ X1, const float* __restrict__ X2,
    float* __restrict__ nrm)
{
    int id = blockIdx.x * blockDim.x + threadIdx.x;
    if (id >= 2 * N) return;
    const float* X = (id < N) ? X1 : X2;
    int r = (id < N) ? id : id - N;
    const float4* p = (const float4*)(X + (size_t)r * D);
    float s = 0.f;
#pragma unroll
    for (int q = 0; q < D / 4; ++q) {
        float4 v = p[q];
        s += v.x * v.x + v.y * v.y + v.z * v.z + v.w * v.w;
    }
    nrm[id] = s;
}

// ---------------------------------------------------------------------------
// Kernel 2 (MFMA, no-LDS hot loop): 6-product 3-way-bf16-split GEMM with
// fragments gathered DIRECTLY from the L2-resident pre-split arrays
// (frag addr: lane&15 -> row, lane>>4 -> k-octet; layouts HW-proven R5/R6).
// Block = 128x128 (4 waves x 64x64 quadrants, no barriers in hot loop).
// Stores -max(sq,0) (monotone proxy; sqrt on winners in topk) + tile maxes.
// ---------------------------------------------------------------------------
__global__ __launch_bounds__(256, 2) void dist_mfma_kernel(
    const short* __restrict__ X1h, const short* __restrict__ X1m,
    const short* __restrict__ X1l, const short* __restrict__ X2h,
    const short* __restrict__ X2m, const short* __restrict__ X2l,
    const float* __restrict__ nrm, float* __restrict__ dst,
    float* __restrict__ tmax)
{
    __shared__ float tpart[128][2];

    const int t    = threadIdx.x;
    const int w    = t >> 6;
    const int lane = t & 63;
    const int rq   = lane >> 4;     // k-octet selector / C row-quad
    const int rlow = lane & 15;     // M/N index within 16-tile

    const int row0 = blockIdx.y * TILE + (w >> 1) * 64;   // wave's 64-row base
    const int col0 = blockIdx.x * TILE + (w & 1) * 64;    // wave's 64-col base

    const short8* A_h = (const short8*)X1h;
    const short8* A_m = (const short8*)X1m;
    const short8* A_l = (const short8*)X1l;
    const short8* B_h = (const short8*)X2h;
    const short8* B_m = (const short8*)X2m;
    const short8* B_l = (const short8*)X2l;

    float4v acc[4][4];
#pragma unroll
    for (int i = 0; i < 4; ++i)
#pragma unroll
        for (int j = 0; j < 4; ++j)
            acc[i][j] = (float4v){0.f, 0.f, 0.f, 0.f};

#pragma unroll
    for (int kc = 0; kc < 2; ++kc) {
        const int kidx = kc * 4 + rq;       // short8 index within a row
        short8 ah[4], am[4], al[4];
#pragma unroll
        for (int tm = 0; tm < 4; ++tm) {
            int idx = (row0 + 16 * tm + rlow) * 8 + kidx;
            ah[tm] = A_h[idx]; am[tm] = A_m[idx]; al[tm] = A_l[idx];
        }
#pragma unroll
        for (int tn = 0; tn < 4; ++tn) {
            int idx = (col0 + 16 * tn + rlow) * 8 + kidx;
            short8 bh = B_h[idx];
            short8 bm = B_m[idx];
            short8 bl = B_l[idx];
#pragma unroll
            for (int tm = 0; tm < 4; ++tm) {
                float4v c = acc[tm][tn];
                c = __builtin_amdgcn_mfma_f32_16x16x32_bf16(ah[tm], bh, c, 0, 0, 0);
                c = __builtin_amdgcn_mfma_f32_16x16x32_bf16(ah[tm], bm, c, 0, 0, 0);
                c = __builtin_amdgcn_mfma_f32_16x16x32_bf16(am[tm], bh, c, 0, 0, 0);
                c = __builtin_amdgcn_mfma_f32_16x16x32_bf16(ah[tm], bl, c, 0, 0, 0);
                c = __builtin_amdgcn_mfma_f32_16x16x32_bf16(al[tm], bh, c, 0, 0, 0);
                c = __builtin_amdgcn_mfma_f32_16x16x32_bf16(am[tm], bm, c, 0, 0, 0);
                acc[tm][tn] = c;
            }
        }
    }

    // ---- epilogue: sq -> -max(sq,0), store, per-row/128-col-tile maxes ----
    float na[4][4], nb[4];
#pragma unroll
    for (int tm = 0; tm < 4; ++tm)
#pragma unroll
        for (int reg = 0; reg < 4; ++reg)
            na[tm][reg] = nrm[row0 + 16 * tm + 4 * rq + reg];
#pragma unroll
    for (int tn = 0; tn < 4; ++tn)
        nb[tn] = nrm[N + col0 + 16 * tn + rlow];

    float rmx[4][4];
#pragma unroll
    for (int tm = 0; tm < 4; ++tm)
#pragma unroll
        for (int reg = 0; reg < 4; ++reg)
            rmx[tm][reg] = -FLT_MAX;

#pragma unroll
    for (int tm = 0; tm < 4; ++tm) {
#pragma unroll
        for (int tn = 0; tn < 4; ++tn) {
#pragma unroll
            for (int reg = 0; reg < 4; ++reg) {
                int rg = row0 + 16 * tm + 4 * rq + reg;    // C/D: row=4*quad+reg
                int cg = col0 + 16 * tn + rlow;            //      col=lane&15
                float sq = na[tm][reg] + nb[tn] - 2.0f * acc[tm][tn][reg];
                float v = -fmaxf(sq, 0.0f);
                dst[(size_t)rg * N + cg] = v;
                rmx[tm][reg] = fmaxf(rmx[tm][reg], v);
            }
        }
    }

    const int rl_base = (w >> 1) * 64;   // row-local base of this wave
#pragma unroll
    for (int tm = 0; tm < 4; ++tm) {
#pragma unroll
        for (int reg = 0; reg < 4; ++reg) {
            float mv = rmx[tm][reg];
            mv = fmaxf(mv, __shfl_xor(mv, 1));
            mv = fmaxf(mv, __shfl_xor(mv, 2));
            mv = fmaxf(mv, __shfl_xor(mv, 4));
            mv = fmaxf(mv, __shfl_xor(mv, 8));
            if (rlow == 0)
                tpart[rl_base + 16 * tm + 4 * rq + reg][w & 1] = mv;
        }
    }
    __syncthreads();
    if ((w & 1) == 0) {
        int row_loc = rl_base + lane;                 // waves 0,2 cover 0..127
        float tv = fmaxf(tpart[row_loc][0], tpart[row_loc][1]);
        tmax[(size_t)(blockIdx.y * TILE + row_loc) * 64 + blockIdx.x] = tv;
    }
}

// ---------------------------------------------------------------------------
// Legacy fp32 dist (fallback when ws too small): writes matrix to dst=out.
// ---------------------------------------------------------------------------
__global__ __launch_bounds__(256, 2) void dist_fp32_kernel(
    const float* __restrict__ X1, const float* __restrict__ X2,
    const float* __restrict__ nrm, float* __restrict__ dst)
{
    __shared__ float As[D * TILE];
    __shared__ float Bs[D * TILE];
    const int t = threadIdx.x;
    const int row0 = blockIdx.y * TILE;
    const int col0 = blockIdx.x * TILE;
#pragma unroll
    for (int p = 0; p < 8; ++p) {
        int lin = p * 256 + t;
        int r   = lin >> 4;
        int d4  = (lin & 15) << 2;
        int g   = (d4 >> 2) & 7;
        int cb  = r ^ (g << 3);
        float4 a = *(const float4*)(X1 + (size_t)(row0 + r) * D + d4);
        As[(d4 + 0) * TILE + cb] = a.x; As[(d4 + 1) * TILE + cb] = a.y;
        As[(d4 + 2) * TILE + cb] = a.z; As[(d4 + 3) * TILE + cb] = a.w;
        float4 b = *(const float4*)(X2 + (size_t)(col0 + r) * D + d4);
        Bs[(d4 + 0) * TILE + cb] = b.x; Bs[(d4 + 1) * TILE + cb] = b.y;
        Bs[(d4 + 2) * TILE + cb] = b.z; Bs[(d4 + 3) * TILE + cb] = b.w;
    }
    __syncthreads();
    const int tx = t & 15;
    const int ty = t >> 4;
    float acc[8][8] = {};
#pragma unroll 8
    for (int k = 0; k < D; ++k) {
        int gk  = (k >> 2) & 7;
        int ab  = k * TILE + ((ty ^ gk) << 3);
        int bb0 = k * TILE + ((4 * tx) ^ (gk << 3));
        float4 a0 = *(const float4*)&As[ab];
        float4 a1 = *(const float4*)&As[ab + 4];
        float4 b0 = *(const float4*)&Bs[bb0];
        float4 b1 = *(const float4*)&Bs[bb0 + 64];
        float av[8] = {a0.x, a0.y, a0.z, a0.w, a1.x, a1.y, a1.z, a1.w};
        float bv[8] = {b0.x, b0.y, b0.z, b0.w, b1.x, b1.y, b1.z, b1.w};
#pragma unroll
        for (int i = 0; i < 8; ++i)
#pragma unroll
            for (int j = 0; j < 8; ++j)
                acc[i][j] += av[i] * bv[j];
    }
    float na[8], nb[8];
#pragma unroll
    for (int i = 0; i < 8; ++i) na[i] = nrm[row0 + 8 * ty + i];
#pragma unroll
    for (int q = 0; q < 4; ++q) {
        nb[q]     = nrm[N + col0 + 4 * tx + q];
        nb[4 + q] = nrm[N + col0 + 64 + 4 * tx + q];
    }
#pragma unroll
    for (int i = 0; i < 8; ++i) {
        float* po = dst + (size_t)(row0 + 8 * ty + i) * N + col0 + 4 * tx;
        float4 o0, o1;
        float* f0 = (float*)&o0;
        float* f1 = (float*)&o1;
#pragma unroll
        for (int q = 0; q < 4; ++q) {
            f0[q] = -fmaxf(na[i] + nb[q] - 2.0f * acc[i][q], 0.0f);
            f1[q] = -fmaxf(na[i] + nb[4 + q] - 2.0f * acc[i][4 + q], 0.0f);
        }
        *(float4*)po = o0; *(float4*)(po + 64) = o1;
    }
}

// ---------------------------------------------------------------------------
// Kernel 3 (PROVEN): one wave per row. thr = 32nd-largest tile-max (sound);
// stream row, compact survivors to LDS u64 keys, NT zero-fill out, 32x shfl
// argmax, sqrt+softmax, scatter.
// ---------------------------------------------------------------------------
__global__ __launch_bounds__(256) void topk_kernel(
    const float* __restrict__ src, float* __restrict__ out,
    float* __restrict__ score_out, const float* __restrict__ tmax,
    int have_tmax)
{
    __shared__ unsigned long long cand[4][CAP];   // 32 KB
    __shared__ int scnt[4];

    const int t    = threadIdx.x;
    const int w    = t >> 6;
    const int lane = t & 63;
    const int r    = blockIdx.x * 4 + w;
    const float4* row4 = (const float4*)(src + (size_t)r * N);
    float4v* rowz = (float4v*)(out + (size_t)r * N);
    float* rowout = out + (size_t)r * N;

    float thr;
    if (have_tmax) {
        float tm = tmax[(size_t)r * 64 + lane];
        unsigned km = ford(tm);
        int rk = 0;
#pragma unroll
        for (int l = 0; l < 64; ++l) {
            unsigned o = __shfl(km, l);
            rk += (o > km || (o == km && l < lane)) ? 1 : 0;
        }
        unsigned long long bm = __ballot(rk == 31);
        thr = __shfl(tm, __ffsll((long long)bm) - 1);
    } else {
        float lm = -FLT_MAX;
#pragma unroll 8
        for (int c = 0; c < 32; ++c) {
            float4 x = row4[c * 64 + lane];
            lm = fmaxf(lm, fmaxf(fmaxf(x.x, x.y), fmaxf(x.z, x.w)));
        }
        thr = lm;
        for (int off = 32; off > 0; off >>= 1)
            thr = fminf(thr, __shfl_xor(thr, off));
    }

    if (lane == 0) scnt[w] = 0;
    __builtin_amdgcn_s_waitcnt(0xC07F);   // lgkmcnt(0)

    const float4v zz = (float4v){0.f, 0.f, 0.f, 0.f};
    for (int c0 = 0; c0 < 32; c0 += 4) {
        float4 xs[4];
#pragma unroll
        for (int u = 0; u < 4; ++u) xs[u] = row4[(c0 + u) * 64 + lane];
#pragma unroll
        for (int u = 0; u < 4; ++u)
            __builtin_nontemporal_store(zz, &rowz[(c0 + u) * 64 + lane]);
#pragma unroll
        for (int u = 0; u < 4; ++u) {
            float vs[4] = {xs[u].x, xs[u].y, xs[u].z, xs[u].w};
#pragma unroll
            for (int q = 0; q < 4; ++q) {
                float v = vs[q];
                if (v >= thr) {
                    int p = atomicAdd(&scnt[w], 1);
                    if (p < CAP) {
                        int j = 4 * ((c0 + u) * 64 + lane) + q;
                        cand[w][p] = ((unsigned long long)ford(v) << 32) |
                                     (unsigned)(8191 - j);
                    }
                }
            }
        }
    }
    __builtin_amdgcn_s_waitcnt(0xC07F);
    const int n = min(scnt[w], CAP);

    unsigned long long mykey = 0ull;
    for (int it = 0; it < TOPK; ++it) {
        unsigned long long b = 0ull; int bp = 0;
        for (int q = lane; q < n; q += 64) {
            unsigned long long kk = cand[w][q];
            if (kk > b) { b = kk; bp = q; }
        }
        for (int off = 32; off > 0; off >>= 1) {
            unsigned long long ob = __shfl_down(b, off);
            int op = __shfl_down(bp, off);
            if (ob > b) { b = ob; bp = op; }
        }
        unsigned long long b0 = __shfl(b, 0);
        int bp0 = __shfl(bp, 0);
        if (lane == it) { mykey = b0; cand[w][bp0] = 0ull; }
    }

    float myv = 0.f; int myj = 0;
    if (lane < TOPK) {
        float sv = finv((unsigned)(mykey >> 32));   // stored -max(sq,0)
        myv = -sqrtf(-sv);
        myj = 8191 - (int)(mykey & 0xFFFFFFFFu);
    }
    float Mx = __shfl(myv, 0);
    float e = (lane < TOPK) ? expf(myv - Mx) : 0.f;
    float Z = e;
    for (int off = 32; off > 0; off >>= 1) Z += __shfl_xor(Z, off);
    float s = e / Z;
    if (lane < TOPK) score_out[(size_t)r * TOPK + lane] = s;

    __builtin_amdgcn_s_waitcnt(0x0F70);   // vmcnt(0): zeros drained
    if (lane < TOPK) rowout[myj] = s;
}

// ---------------------------------------------------------------------------
extern "C" void kernel_launch(void* const* d_in, const int* in_sizes, int n_in,
                              void* d_out, int out_size, void* d_ws, size_t ws_size,
                              hipStream_t stream)
{
    const float* X1 = (const float*)d_in[0];
    const float* X2 = (const float*)d_in[1];
    float* out = (float*)d_out;

    // ws layout: nrm | tmax | 6 bf16 split arrays | dense matrix
    float* nrm  = (float*)d_ws;                   // 2N floats
    float* tmax = nrm + 2 * N;                    // N*64 floats (2 MB)
    short* X1h  = (short*)(tmax + (size_t)N * 64);
    short* X1m  = X1h + (size_t)N * 64;
    short* X1l  = X1m + (size_t)N * 64;
    short* X2h  = X1l + (size_t)N * 64;
    short* X2m  = X2h + (size_t)N * 64;
    short* X2l  = X2m + (size_t)N * 64;           // 6 MB of splits
    float* dmat = (float*)(X2l + (size_t)N * 64); // N*N floats (256 MB)

    size_t need_full = (size_t)((char*)(dmat + (size_t)N * N) - (char*)d_ws);
    int fastmode = (ws_size >= need_full) ? 1 : 0;

    norms_kernel<<<(2 * N + 255) / 256, 256, 0, stream>>>(X1, X2, nrm);
    dim3 grid(N / TILE, N / TILE);

    if (fastmode) {
        presplit_kernel<<<(2 * N * 8 + 255) / 256, 256, 0, stream>>>(
            X1, X2, X1h, X1m, X1l, X2h, X2m, X2l);
        dist_mfma_kernel<<<grid, 256, 0, stream>>>(
            X1h, X1m, X1l, X2h, X2m, X2l, nrm, dmat, tmax);
        topk_kernel<<<N / 4, 256, 0, stream>>>(dmat, out, out + (size_t)N * N,
                                               tmax, 1);
    } else {
        dist_fp32_kernel<<<grid, 256, 0, stream>>>(X1, X2, nrm, out);
        topk_kernel<<<N / 4, 256, 0, stream>>>(out, out, out + (size_t)N * N,
                                               nullptr, 0);
    }
}